// Round 6
// baseline (3581.378 us; speedup 1.0000x reference)
//
#include <hip/hip_runtime.h>
#include <cstdint>
#include <cstddef>

#define B_   16
#define L_   8192
#define D_   256
#define NB_  8
#define NCHB 16    // chunks per batch row (512 tokens each)
#define NT2  32    // tasks per (b,n): NCHB * 2 (tp-split)

// ws offsets (floats)
static const long OFF_QK   = 0;      // 2048
static const long OFF_QB   = 2048;   // 8
static const long OFF_PART = 4096;   // 4096 tasks * 2048 floats
static const long PART_FLOATS = 4096L * 2048;
static const long OFF_PSE  = OFF_PART + PART_FLOATS;  // 4096 * 8

// ---------------------------------------------------------------- k_setup
// 8 blocks, block h: qk[h][e] = (sum_d q[h*32+d] * Wk[256+h*32+d][e]) / sqrt(32).
__global__ __launch_bounds__(256) void k_setup(const float* __restrict__ query,
                                               const float* __restrict__ W,
                                               const float* __restrict__ bias,
                                               float* __restrict__ ws) {
    __shared__ float q_s[256];
    int t = threadIdx.x;
    int h = blockIdx.x;
    float acc = bias[t];
    const float* wr = W + (long)t * 256;
    #pragma unroll 8
    for (int e = 0; e < 256; e += 4) {
        float4 qv = *(const float4*)(query + e);
        float4 wv = *(const float4*)(wr + e);
        acc += qv.x * wv.x + qv.y * wv.y + qv.z * wv.z + qv.w * wv.w;
    }
    q_s[t] = acc;
    __syncthreads();
    const float rs = 0.17677669529663687f; // 1/sqrt(32)
    float s = 0.f;
    #pragma unroll 8
    for (int d = 0; d < 32; ++d) {
        int r = 256 + h * 32 + d;
        s += q_s[h * 32 + d] * W[(long)r * 256 + t];
    }
    ws[OFF_QK + h * 256 + t] = s * rs;
    if (t < 64) {
        float v = (t < 32) ? q_s[h * 32 + t] * bias[256 + h * 32 + t] : 0.f;
        v += __shfl_down(v, 16);
        v += __shfl_down(v, 8);
        v += __shfl_down(v, 4);
        v += __shfl_down(v, 2);
        v += __shfl_down(v, 1);
        if (t == 0) ws[OFF_QB + h] = v * rs;
    }
}

// 3-step butterfly over low 3 lane bits: p0..p7 per-lane partials for h=0..7.
// Result: lane (tk,ep) holds the full octet sum of p[ep].
__device__ __forceinline__ float reduce_ep(float p0, float p1, float p2, float p3,
                                           float p4, float p5, float p6, float p7, int ep) {
    bool b1 = (ep & 1) != 0;
    float s0 = b1 ? p0 : p1, k0 = b1 ? p1 : p0;
    float s1 = b1 ? p2 : p3, k1 = b1 ? p3 : p2;
    float s2 = b1 ? p4 : p5, k2 = b1 ? p5 : p4;
    float s3 = b1 ? p6 : p7, k3 = b1 ? p7 : p6;
    float n0 = k0 + __shfl_xor(s0, 1);
    float n1 = k1 + __shfl_xor(s1, 1);
    float n2 = k2 + __shfl_xor(s2, 1);
    float n3 = k3 + __shfl_xor(s3, 1);
    bool b2 = (ep & 2) != 0;
    float t0s = b2 ? n0 : n1, t0k = b2 ? n1 : n0;
    float t1s = b2 ? n2 : n3, t1k = b2 ? n3 : n2;
    float m0 = t0k + __shfl_xor(t0s, 2);
    float m1 = t1k + __shfl_xor(t1s, 2);
    bool b4 = (ep & 4) != 0;
    float us = b4 ? m0 : m1, uk = b4 ? m1 : m0;
    return uk + __shfl_xor(us, 4);
}

__device__ __forceinline__ float hsum4(float4 a) { return (a.x + a.y) + (a.z + a.w); }

// Async global->LDS, 16B per lane, no VGPR landing zone.
__device__ __forceinline__ void gld16(const float* g, float* l) {
    __builtin_amdgcn_global_load_lds(
        (const __attribute__((address_space(1))) void*)g,
        (__attribute__((address_space(3))) void*)l, 16, 0, 0);
}

// ---------------------------------------------------------------- k_main
// One block (512 thr) per (b, 512-token chunk). Streams x ONCE through a
// double-buffered 64KB LDS window via global_load_lds (deep async pipe,
// counted vmcnt, raw barriers — stage(w+1) stays in flight across compute(w)).
// Per window: scores for all 64 tokens (round-2 (tk,ep) layout, conflict-free
// LDS reads), exp -> w_lds; then pool: thread (tp,e) accumulates acc[n][h] in
// registers via wave-uniform switch on bid. Invalid tokens: w=0 (no screening,
// no divergence). tp-split tasks (NT2=32 per (b,n)) avoid cross-wave reduce.
__global__ __launch_bounds__(512) void k_main(const float* __restrict__ x,
                                              const unsigned char* __restrict__ mask,
                                              const int* __restrict__ bid,
                                              const float* __restrict__ ws,
                                              float* __restrict__ part,
                                              float* __restrict__ pse) {
    __shared__ alignas(16) float xt[2][16384];   // 2 x 64KB window
    __shared__ alignas(16) float qks[2056];      // qk[8][256] + qb[8]
    __shared__ alignas(16) float wls[512];       // w[64 tok][8 h]
    __shared__ int bidl[512];
    __shared__ int maskl[512];

    const int tid  = threadIdx.x;
    const int lane = tid & 63;
    const int widx = tid >> 6;
    const int bI   = blockIdx.x >> 4;  // batch
    const int ch   = blockIdx.x & 15;  // chunk

    // ---------------- prologue: qk table + chunk mask/bid into LDS
    for (int i = tid; i < 2056; i += 512) qks[i] = ws[i];
    {
        // mask dtype detection: packed 0/1 bool bytes read as int32 give a word
        // > 1 with probability 1-8^-64; a genuine int32 0/1 mask never does.
        const int* mi = (const int*)mask;
        bool bytemode = __ballot((unsigned)mi[lane] > 1u) != 0ull;
        long gt = (long)bI * L_ + ch * 512 + tid;
        maskl[tid] = bytemode ? (mask[gt] != 0) : (mi[gt] != 0);
        bidl[tid]  = bid[gt];
    }
    __syncthreads();   // full drain ok here (before any staging)

    const float* xg = x + (long)bI * (L_ * D_) + (long)ch * (512 * D_);

    float accA[8][8];
    #pragma unroll
    for (int n = 0; n < 8; ++n) {
        #pragma unroll
        for (int h = 0; h < 8; ++h) accA[n][h] = 0.f;
    }
    float seA[8] = {0.f, 0.f, 0.f, 0.f, 0.f, 0.f, 0.f, 0.f};

    // stage window 0 -> buf 0 (8 x 16B per thread = 64KB per block)
    {
        const float* g = xg + tid * 4;
        float* l = &xt[0][tid * 4];
        #pragma unroll
        for (int r = 0; r < 8; ++r) gld16(g + r * 2048, l + r * 2048);
    }

    const int tk = lane >> 3, ep = lane & 7;
    const int tp = widx >> 2;                  // token parity handled by this wave
    const int e  = ((widx & 3) << 6) | lane;   // e-component owned in pool phase

    for (int w = 0; w < 8; ++w) {
        const int bufI = w & 1;
        if (w < 7) {
            const float* g = xg + (long)(w + 1) * 16384 + tid * 4;
            float* l = &xt[bufI ^ 1][tid * 4];
            #pragma unroll
            for (int r = 0; r < 8; ++r) gld16(g + r * 2048, l + r * 2048);
            asm volatile("s_waitcnt vmcnt(8)" ::: "memory");  // window w staged
        } else {
            asm volatile("s_waitcnt vmcnt(0)" ::: "memory");
        }
        __builtin_amdgcn_s_barrier();   // B1: xt[bufI] visible to all waves

        // ---- scores: wave widx -> tokens widx*8 .. +8 (round-2 proven layout)
        {
            const int trow = widx * 8 + tk;                 // window-local token
            const float* xrow = &xt[bufI][trow * 256 + ep * 4];
            const float* qkb  = &qks[ep * 4];
            float4 a[8];
            #pragma unroll
            for (int h2 = 0; h2 < 8; ++h2) a[h2] = make_float4(0.f, 0.f, 0.f, 0.f);
            #pragma unroll
            for (int k = 0; k < 8; ++k) {
                float4 xv = *(const float4*)(xrow + 32 * k);
                #pragma unroll
                for (int h2 = 0; h2 < 8; ++h2) {
                    float4 qv = *(const float4*)(qkb + h2 * 256 + 32 * k);
                    a[h2].x += xv.x * qv.x; a[h2].y += xv.y * qv.y;
                    a[h2].z += xv.z * qv.z; a[h2].w += xv.w * qv.w;
                }
            }
            float s = reduce_ep(hsum4(a[0]), hsum4(a[1]), hsum4(a[2]), hsum4(a[3]),
                                hsum4(a[4]), hsum4(a[5]), hsum4(a[6]), hsum4(a[7]), ep);
            s += qks[2048 + ep];
            float wgt = maskl[w * 64 + trow] ? __expf(s) : 0.f;
            wls[trow * 8 + ep] = wgt;
        }
        asm volatile("s_waitcnt lgkmcnt(0)" ::: "memory");
        __builtin_amdgcn_s_barrier();   // B2: wls visible

        // ---- pool: 32 tokens for this tp; acc[n][h] in registers
        for (int i = 0; i < 32; ++i) {
            const int t = i * 2 + tp;
            int n_t = __builtin_amdgcn_readfirstlane(bidl[w * 64 + t]);
            float xval = xt[bufI][t * 256 + e];
            float4 w0 = *(const float4*)&wls[t * 8];
            float4 w1 = *(const float4*)&wls[t * 8 + 4];
            float sev = wls[t * 8 + (e & 7)];
            #define POOL_ARM(N)                                                   \
                { accA[N][0] += w0.x * xval; accA[N][1] += w0.y * xval;            \
                  accA[N][2] += w0.z * xval; accA[N][3] += w0.w * xval;            \
                  accA[N][4] += w1.x * xval; accA[N][5] += w1.y * xval;            \
                  accA[N][6] += w1.z * xval; accA[N][7] += w1.w * xval;            \
                  if (e < 8) seA[N] += sev; }
            switch (n_t) {
                case 0: POOL_ARM(0); break;
                case 1: POOL_ARM(1); break;
                case 2: POOL_ARM(2); break;
                case 3: POOL_ARM(3); break;
                case 4: POOL_ARM(4); break;
                case 5: POOL_ARM(5); break;
                case 6: POOL_ARM(6); break;
                default: POOL_ARM(7); break;
            }
            #undef POOL_ARM
        }
        __builtin_amdgcn_s_barrier();   // B3: pool(w) done before overwrites
    }

    // ---------------- epilogue: per-thread direct stores (no cross-wave reduce)
    const int task0 = (bI * NB_) * NT2 + ch * 2 + tp;
    #pragma unroll
    for (int n = 0; n < 8; ++n) {
        long tb2 = (long)(task0 + n * NT2) * 2048;
        #pragma unroll
        for (int h2 = 0; h2 < 8; ++h2)
            part[tb2 + h2 * 256 + e] = accA[n][h2];
        if (e < 8) pse[(long)(task0 + n * NT2) * 8 + e] = seA[n];
    }
}

// ---------------------------------------------------------------- k_epi
// One block per (n,b): reduce partials (fixed order), normalize, wv-project,
// out-project, LayerNorm, zero empty backends, write out[b][n][:].
template <int NCH>
__global__ __launch_bounds__(256) void k_epi(const float* __restrict__ part,
                                             const float* __restrict__ pse,
                                             const float* __restrict__ W,
                                             const float* __restrict__ ib,
                                             const float* __restrict__ Wo,
                                             const float* __restrict__ ob,
                                             const float* __restrict__ gamma,
                                             const float* __restrict__ beta,
                                             float* __restrict__ out) {
    __shared__ float pn[2048];
    __shared__ float ses[8];
    __shared__ float ctx_s[256];
    __shared__ float r1[4], r2[4];
    int n = blockIdx.x & 7, b = blockIdx.x >> 3;
    int t = threadIdx.x;
    int tbase = b * (NB_ * NCH) + n * NCH;
    if (t < 8) {
        float s = 0.f;
        for (int sub = 0; sub < NCH; ++sub) s += pse[(long)(tbase + sub) * 8 + t];
        ses[t] = s;
    }
    __syncthreads();
    bool has = ses[0] > 0.f;
    for (int j = 0; j < 8; ++j) {
        int idx = j * 256 + t;
        int h = idx >> 8;
        float s = 0.f;
        for (int sub = 0; sub < NCH; ++sub) s += part[(long)(tbase + sub) * 2048 + idx];
        pn[idx] = has ? s / ses[h] : 0.f;
    }
    __syncthreads();
    int h = t >> 5;
    float c = ib[512 + t];
    {
        const float* wr = W + (long)(512 + t) * 256;
        const float* ph = pn + h * 256;
        for (int e = 0; e < 256; e += 4) {
            float4 wv4 = *(const float4*)(wr + e);
            float4 pv4 = *(const float4*)(ph + e);
            c += wv4.x * pv4.x + wv4.y * pv4.y + wv4.z * pv4.z + wv4.w * pv4.w;
        }
    }
    ctx_s[t] = c;
    __syncthreads();
    float o = ob[t];
    {
        const float* wr = Wo + (long)t * 256;
        for (int d = 0; d < 256; d += 4) {
            float4 wv4 = *(const float4*)(wr + d);
            float4 cv4 = *(const float4*)(ctx_s + d);
            o += wv4.x * cv4.x + wv4.y * cv4.y + wv4.z * cv4.z + wv4.w * cv4.w;
        }
    }
    float s1 = o, s2 = o * o;
    #pragma unroll
    for (int off = 32; off >= 1; off >>= 1) {
        s1 += __shfl_down(s1, off);
        s2 += __shfl_down(s2, off);
    }
    if ((t & 63) == 0) { r1[t >> 6] = s1; r2[t >> 6] = s2; }
    __syncthreads();
    float S1 = r1[0] + r1[1] + r1[2] + r1[3];
    float S2 = r2[0] + r2[1] + r2[2] + r2[3];
    float mu = S1 * (1.f / 256.f);
    float var = S2 * (1.f / 256.f) - mu * mu;
    float rr = rsqrtf(var + 1e-5f);
    float res = ((o - mu) * rr * gamma[t] + beta[t]) * (has ? 1.f : 0.f);
    out[((long)b * 8 + n) * 256 + t] = res;
}

// ---------------------------------------------------------------- launch
extern "C" void kernel_launch(void* const* d_in, const int* in_sizes, int n_in,
                              void* d_out, int out_size, void* d_ws, size_t ws_size,
                              hipStream_t stream) {
    const float* x     = (const float*)d_in[0];
    const float* query = (const float*)d_in[1];
    const float* W     = (const float*)d_in[2];
    const float* ib    = (const float*)d_in[3];
    const float* Wo    = (const float*)d_in[4];
    const float* ob    = (const float*)d_in[5];
    const float* gamma = (const float*)d_in[6];
    const float* beta  = (const float*)d_in[7];
    const unsigned char* mask = (const unsigned char*)d_in[8];
    const int* bid     = (const int*)d_in[9];
    float* out = (float*)d_out;
    float* ws  = (float*)d_ws;

    float* part = ws + OFF_PART;
    float* pse  = ws + OFF_PSE;

    k_setup<<<8, 256, 0, stream>>>(query, W, ib, ws);
    k_main<<<B_ * NCHB, 512, 0, stream>>>(x, mask, bid, ws, part, pse);
    k_epi<NT2><<<B_ * NB_, 256, 0, stream>>>(part, pse, W, ib, Wo, ob, gamma, beta, out);
}

// Round 7
// 237.483 us; speedup vs baseline: 15.0806x; 15.0806x over previous
//
#include <hip/hip_runtime.h>
#include <cstdint>
#include <cstddef>

#define B_   16
#define L_   8192
#define D_   256
#define NB_  8
#define NCHB 16    // chunks per batch row (512 tokens each); 16*16 = 256 blocks = 1/CU

// ws offsets (floats)
static const long OFF_QK   = 0;      // 2048
static const long OFF_QB   = 2048;   // 8
static const long OFF_PART = 4096;   // 2048 tasks * 2048 floats
static const long PART_FLOATS = 2048L * 2048;
static const long OFF_PSE  = OFF_PART + PART_FLOATS;  // 2048 * 8

// ---------------------------------------------------------------- k_setup
// 8 blocks, block h: qk[h][e] = (sum_d q[h*32+d] * Wk[256+h*32+d][e]) / sqrt(32).
__global__ __launch_bounds__(256) void k_setup(const float* __restrict__ query,
                                               const float* __restrict__ W,
                                               const float* __restrict__ bias,
                                               float* __restrict__ ws) {
    __shared__ float q_s[256];
    int t = threadIdx.x;
    int h = blockIdx.x;
    float acc = bias[t];
    const float* wr = W + (long)t * 256;
    #pragma unroll 8
    for (int e = 0; e < 256; e += 4) {
        float4 qv = *(const float4*)(query + e);
        float4 wv = *(const float4*)(wr + e);
        acc += qv.x * wv.x + qv.y * wv.y + qv.z * wv.z + qv.w * wv.w;
    }
    q_s[t] = acc;
    __syncthreads();
    const float rs = 0.17677669529663687f; // 1/sqrt(32)
    float s = 0.f;
    #pragma unroll 8
    for (int d = 0; d < 32; ++d) {
        int r = 256 + h * 32 + d;
        s += q_s[h * 32 + d] * W[(long)r * 256 + t];
    }
    ws[OFF_QK + h * 256 + t] = s * rs;
    if (t < 64) {
        float v = (t < 32) ? q_s[h * 32 + t] * bias[256 + h * 32 + t] : 0.f;
        v += __shfl_down(v, 16);
        v += __shfl_down(v, 8);
        v += __shfl_down(v, 4);
        v += __shfl_down(v, 2);
        v += __shfl_down(v, 1);
        if (t == 0) ws[OFF_QB + h] = v * rs;
    }
}

// 3-step butterfly over low 3 lane bits: p0..p7 per-lane partials for h=0..7.
// Octet (fixed tk, ep=0..7) spans all 256 e -> output: lane (tk,ep) holds the
// COMPLETE score for head ep of token tk.
__device__ __forceinline__ float reduce_ep(float p0, float p1, float p2, float p3,
                                           float p4, float p5, float p6, float p7, int ep) {
    bool b1 = (ep & 1) != 0;
    float s0 = b1 ? p0 : p1, k0 = b1 ? p1 : p0;
    float s1 = b1 ? p2 : p3, k1 = b1 ? p3 : p2;
    float s2 = b1 ? p4 : p5, k2 = b1 ? p5 : p4;
    float s3 = b1 ? p6 : p7, k3 = b1 ? p7 : p6;
    float n0 = k0 + __shfl_xor(s0, 1);
    float n1 = k1 + __shfl_xor(s1, 1);
    float n2 = k2 + __shfl_xor(s2, 1);
    float n3 = k3 + __shfl_xor(s3, 1);
    bool b2 = (ep & 2) != 0;
    float t0s = b2 ? n0 : n1, t0k = b2 ? n1 : n0;
    float t1s = b2 ? n2 : n3, t1k = b2 ? n3 : n2;
    float m0 = t0k + __shfl_xor(t0s, 2);
    float m1 = t1k + __shfl_xor(t1s, 2);
    bool b4 = (ep & 4) != 0;
    float us = b4 ? m0 : m1, uk = b4 ? m1 : m0;
    return uk + __shfl_xor(us, 4);
}

// Async global->LDS, 16B per lane, no VGPR landing zone.
__device__ __forceinline__ void gld16(const float* g, float* l) {
    __builtin_amdgcn_global_load_lds(
        (const __attribute__((address_space(1))) void*)g,
        (__attribute__((address_space(3))) void*)l, 16, 0, 0);
}

// ---------------------------------------------------------------- k_main
// One block (512 thr) per (b, 512-token chunk); 256 blocks = 1 per CU.
// Streams x once through a double-buffered 64KB LDS window via global_load_lds
// (counted vmcnt(8), raw barriers -> next window's loads stay in flight across
// compute). Per 64-token window:
//   scores: wave widx -> tokens widx*8..+8, (tk,ep) lanes; qk read from LDS as
//           same-address broadcasts (bank 4*ep, conflict-free); 8 scalar p acc;
//           reduce_ep -> w = exp(score) (0 if masked) -> wls.
//   pool:   thread (g=tid>>8, e=tid&255) owns acc[n][h'=4] (32 VGPR, g selects
//           head-quad); wave-uniform scalar branch on bid; invalid tokens
//           skipped. One partial task per (block, n); no cross-wave reduce.
__global__ __launch_bounds__(512) void k_main(const float* __restrict__ x,
                                              const unsigned char* __restrict__ mask,
                                              const int* __restrict__ bid,
                                              const float* __restrict__ ws,
                                              float* __restrict__ part,
                                              float* __restrict__ pse) {
    __shared__ alignas(16) float xt[2][16384];   // 2 x 64KB window
    __shared__ alignas(16) float qks[2056];      // qk[8][256] + qb[8]
    __shared__ alignas(16) float wls[512];       // w[64 tok][8 h]
    __shared__ int bidl[512];
    __shared__ int maskl[512];

    const int tid  = threadIdx.x;
    const int lane = tid & 63;
    const int widx = tid >> 6;
    const int bI   = blockIdx.x >> 4;  // batch
    const int ch   = blockIdx.x & 15;  // chunk

    // ---------------- prologue
    for (int i = tid; i < 2056; i += 512) qks[i] = ws[i];
    {
        // mask dtype detection: packed 0/1 bool bytes read as int32 give a word
        // > 1 with probability 1-8^-64; a genuine int32 0/1 mask never does.
        const int* mi = (const int*)mask;
        bool bytemode = __ballot((unsigned)mi[lane] > 1u) != 0ull;
        long gt = (long)bI * L_ + ch * 512 + tid;
        maskl[tid] = bytemode ? (mask[gt] != 0) : (mi[gt] != 0);
        bidl[tid]  = bid[gt];
    }
    __syncthreads();   // prologue drain (before any staging)

    const float* xg = x + (long)bI * (L_ * D_) + (long)ch * (512 * D_);

    const int tk = lane >> 3, ep = lane & 7;
    const int g  = tid >> 8;          // head-quad owner in pool phase
    const int e  = tid & 255;         // e-column owner in pool phase

    float acc[8][4];
    #pragma unroll
    for (int n = 0; n < 8; ++n) {
        #pragma unroll
        for (int j = 0; j < 4; ++j) acc[n][j] = 0.f;
    }
    float se[8] = {0.f, 0.f, 0.f, 0.f, 0.f, 0.f, 0.f, 0.f};

    // stage window 0 -> buf 0 (8 x 16B per thread = 64KB per block)
    {
        const float* gp = xg + tid * 4;
        float* lp = &xt[0][tid * 4];
        #pragma unroll
        for (int r = 0; r < 8; ++r) gld16(gp + r * 2048, lp + r * 2048);
    }

    for (int w = 0; w < 8; ++w) {
        const int bufI = w & 1;
        if (w < 7) {
            const float* gp = xg + (long)(w + 1) * 16384 + tid * 4;
            float* lp = &xt[bufI ^ 1][tid * 4];
            #pragma unroll
            for (int r = 0; r < 8; ++r) gld16(gp + r * 2048, lp + r * 2048);
            asm volatile("s_waitcnt vmcnt(8)" ::: "memory");  // window w landed
        } else {
            asm volatile("s_waitcnt vmcnt(0)" ::: "memory");
        }
        __builtin_amdgcn_s_barrier();   // B1: xt[bufI] visible

        // ---- scores (8 scalar p's, qk broadcast from LDS)
        {
            const int trow = widx * 8 + tk;
            const float* xrow = &xt[bufI][trow * 256 + ep * 4];
            const float* qkb  = &qks[ep * 4];
            float p0 = 0.f, p1 = 0.f, p2 = 0.f, p3 = 0.f;
            float p4 = 0.f, p5 = 0.f, p6 = 0.f, p7 = 0.f;
            #pragma unroll
            for (int k = 0; k < 8; ++k) {
                float4 xv = *(const float4*)(xrow + 32 * k);
                float4 q0 = *(const float4*)(qkb + 0 * 256 + 32 * k);
                float4 q1 = *(const float4*)(qkb + 1 * 256 + 32 * k);
                float4 q2 = *(const float4*)(qkb + 2 * 256 + 32 * k);
                float4 q3 = *(const float4*)(qkb + 3 * 256 + 32 * k);
                float4 q4 = *(const float4*)(qkb + 4 * 256 + 32 * k);
                float4 q5 = *(const float4*)(qkb + 5 * 256 + 32 * k);
                float4 q6 = *(const float4*)(qkb + 6 * 256 + 32 * k);
                float4 q7 = *(const float4*)(qkb + 7 * 256 + 32 * k);
                p0 += xv.x*q0.x + xv.y*q0.y + xv.z*q0.z + xv.w*q0.w;
                p1 += xv.x*q1.x + xv.y*q1.y + xv.z*q1.z + xv.w*q1.w;
                p2 += xv.x*q2.x + xv.y*q2.y + xv.z*q2.z + xv.w*q2.w;
                p3 += xv.x*q3.x + xv.y*q3.y + xv.z*q3.z + xv.w*q3.w;
                p4 += xv.x*q4.x + xv.y*q4.y + xv.z*q4.z + xv.w*q4.w;
                p5 += xv.x*q5.x + xv.y*q5.y + xv.z*q5.z + xv.w*q5.w;
                p6 += xv.x*q6.x + xv.y*q6.y + xv.z*q6.z + xv.w*q6.w;
                p7 += xv.x*q7.x + xv.y*q7.y + xv.z*q7.z + xv.w*q7.w;
            }
            float s = reduce_ep(p0, p1, p2, p3, p4, p5, p6, p7, ep);
            s += qks[2048 + ep];
            float wgt = maskl[w * 64 + trow] ? __expf(s) : 0.f;
            wls[trow * 8 + ep] = wgt;
        }
        asm volatile("s_waitcnt lgkmcnt(0)" ::: "memory");
        __builtin_amdgcn_s_barrier();   // B2: wls visible

        // ---- pool: 64 tokens; thread (g,e) updates acc[n][0..4)
        for (int t = 0; t < 64; ++t) {
            if (__builtin_amdgcn_readfirstlane(maskl[w * 64 + t]) == 0) continue;
            int n_t = __builtin_amdgcn_readfirstlane(bidl[w * 64 + t]);
            float xval = xt[bufI][t * 256 + e];
            float4 w4 = *(const float4*)&wls[t * 8 + g * 4];
            float sev = wls[t * 8 + (e & 7)];
            #define POOL_ARM(N)                                                   \
                { acc[N][0] += w4.x * xval; acc[N][1] += w4.y * xval;              \
                  acc[N][2] += w4.z * xval; acc[N][3] += w4.w * xval;              \
                  if (g == 0 && e < 8) se[N] += sev; }
            switch (n_t) {
                case 0: POOL_ARM(0); break;
                case 1: POOL_ARM(1); break;
                case 2: POOL_ARM(2); break;
                case 3: POOL_ARM(3); break;
                case 4: POOL_ARM(4); break;
                case 5: POOL_ARM(5); break;
                case 6: POOL_ARM(6); break;
                default: POOL_ARM(7); break;
            }
            #undef POOL_ARM
        }
        __builtin_amdgcn_s_barrier();   // B3: pool(w) done before xt[bufI] reuse
    }

    // ---------------- epilogue: one task per (block,n); disjoint h-quads
    const int blk = blockIdx.x;
    #pragma unroll
    for (int n = 0; n < 8; ++n) {
        long tb = (long)(blk * 8 + n) * 2048;
        #pragma unroll
        for (int j = 0; j < 4; ++j)
            part[tb + (g * 4 + j) * 256 + e] = acc[n][j];
        if (g == 0 && e < 8) pse[(long)(blk * 8 + n) * 8 + e] = se[n];
    }
}

// ---------------------------------------------------------------- k_epi
// One block per (n,b): reduce the 16 chunk-partials (fixed order), normalize,
// wv-project, out-project, LayerNorm, zero empty backends, write out[b][n][:].
__global__ __launch_bounds__(256) void k_epi(const float* __restrict__ part,
                                             const float* __restrict__ pse,
                                             const float* __restrict__ W,
                                             const float* __restrict__ ib,
                                             const float* __restrict__ Wo,
                                             const float* __restrict__ ob,
                                             const float* __restrict__ gamma,
                                             const float* __restrict__ beta,
                                             float* __restrict__ out) {
    __shared__ float pn[2048];
    __shared__ float ses[8];
    __shared__ float ctx_s[256];
    __shared__ float r1[4], r2[4];
    int n = blockIdx.x & 7, b = blockIdx.x >> 3;
    int t = threadIdx.x;
    if (t < 8) {
        float s = 0.f;
        for (int chv = 0; chv < NCHB; ++chv)
            s += pse[(long)(b * 128 + chv * 8 + n) * 8 + t];
        ses[t] = s;
    }
    __syncthreads();
    bool has = ses[0] > 0.f;
    for (int j = 0; j < 8; ++j) {
        int idx = j * 256 + t;
        int h = idx >> 8;
        float s = 0.f;
        for (int chv = 0; chv < NCHB; ++chv)
            s += part[(long)(b * 128 + chv * 8 + n) * 2048 + idx];
        pn[idx] = has ? s / ses[h] : 0.f;
    }
    __syncthreads();
    int h = t >> 5;
    float c = ib[512 + t];
    {
        const float* wr = W + (long)(512 + t) * 256;
        const float* ph = pn + h * 256;
        for (int e = 0; e < 256; e += 4) {
            float4 wv4 = *(const float4*)(wr + e);
            float4 pv4 = *(const float4*)(ph + e);
            c += wv4.x * pv4.x + wv4.y * pv4.y + wv4.z * pv4.z + wv4.w * pv4.w;
        }
    }
    ctx_s[t] = c;
    __syncthreads();
    float o = ob[t];
    {
        const float* wr = Wo + (long)t * 256;
        for (int d = 0; d < 256; d += 4) {
            float4 wv4 = *(const float4*)(wr + d);
            float4 cv4 = *(const float4*)(ctx_s + d);
            o += wv4.x * cv4.x + wv4.y * cv4.y + wv4.z * cv4.z + wv4.w * cv4.w;
        }
    }
    float s1 = o, s2 = o * o;
    #pragma unroll
    for (int off = 32; off >= 1; off >>= 1) {
        s1 += __shfl_down(s1, off);
        s2 += __shfl_down(s2, off);
    }
    if ((t & 63) == 0) { r1[t >> 6] = s1; r2[t >> 6] = s2; }
    __syncthreads();
    float S1 = r1[0] + r1[1] + r1[2] + r1[3];
    float S2 = r2[0] + r2[1] + r2[2] + r2[3];
    float mu = S1 * (1.f / 256.f);
    float var = S2 * (1.f / 256.f) - mu * mu;
    float rr = rsqrtf(var + 1e-5f);
    float res = ((o - mu) * rr * gamma[t] + beta[t]) * (has ? 1.f : 0.f);
    out[((long)b * 8 + n) * 256 + t] = res;
}

// ---------------------------------------------------------------- launch
extern "C" void kernel_launch(void* const* d_in, const int* in_sizes, int n_in,
                              void* d_out, int out_size, void* d_ws, size_t ws_size,
                              hipStream_t stream) {
    const float* x     = (const float*)d_in[0];
    const float* query = (const float*)d_in[1];
    const float* W     = (const float*)d_in[2];
    const float* ib    = (const float*)d_in[3];
    const float* Wo    = (const float*)d_in[4];
    const float* ob    = (const float*)d_in[5];
    const float* gamma = (const float*)d_in[6];
    const float* beta  = (const float*)d_in[7];
    const unsigned char* mask = (const unsigned char*)d_in[8];
    const int* bid     = (const int*)d_in[9];
    float* out = (float*)d_out;
    float* ws  = (float*)d_ws;

    float* part = ws + OFF_PART;
    float* pse  = ws + OFF_PSE;

    k_setup<<<8, 256, 0, stream>>>(query, W, ib, ws);
    k_main<<<B_ * NCHB, 512, 0, stream>>>(x, mask, bid, ws, part, pse);
    k_epi<<<B_ * NB_, 256, 0, stream>>>(part, pse, W, ib, Wo, ob, gamma, beta, out);
}